// Round 4
// baseline (322.833 us; speedup 1.0000x reference)
//
#include <hip/hip_runtime.h>

// GCN forward: 2x GCNConv(64->64) + MLP(64->128->10), fp32, pull-based CSR.

#define NFEAT 64

// ---- CSR build ----------------------------------------------------------

__global__ void k_hist(const int* __restrict__ row, int* __restrict__ cnt, int ne) {
    int i = blockIdx.x * blockDim.x + threadIdx.x;
    int st = gridDim.x * blockDim.x;
    for (; i < ne; i += st) atomicAdd(&cnt[row[i]], 1);
}

__global__ void k_scanA(const int* __restrict__ cnt, int* __restrict__ bsum, int n) {
    __shared__ int s[256];
    int tid = threadIdx.x;
    int i = blockIdx.x * 256 + tid;
    s[tid] = (i < n) ? cnt[i] : 0;
    __syncthreads();
    for (int d = 128; d > 0; d >>= 1) {
        if (tid < d) s[tid] += s[tid + d];
        __syncthreads();
    }
    if (tid == 0) bsum[blockIdx.x] = s[0];
}

__global__ void k_scanB(const int* __restrict__ bsum, int* __restrict__ bpre, int nb) {
    __shared__ int s[256];
    int tid = threadIdx.x;
    int v = (tid < nb) ? bsum[tid] : 0;
    s[tid] = v;
    __syncthreads();
    for (int d = 1; d < 256; d <<= 1) {
        int t = (tid >= d) ? s[tid - d] : 0;
        __syncthreads();
        s[tid] += t;
        __syncthreads();
    }
    if (tid < nb) bpre[tid] = s[tid] - v;  // exclusive
}

// exclusive per-element offsets + dis = rsqrt(1+deg)
__global__ void k_scanC(const int* __restrict__ cnt, const int* __restrict__ bpre,
                        int* __restrict__ off, float* __restrict__ dis, int n) {
    __shared__ int s[256];
    int tid = threadIdx.x;
    int i = blockIdx.x * 256 + tid;
    int v = (i < n) ? cnt[i] : 0;
    s[tid] = v;
    __syncthreads();
    for (int d = 1; d < 256; d <<= 1) {
        int t = (tid >= d) ? s[tid - d] : 0;
        __syncthreads();
        s[tid] += t;
        __syncthreads();
    }
    if (i < n) {
        off[i] = bpre[blockIdx.x] + s[tid] - v;
        dis[i] = rsqrtf(1.0f + (float)v);
    }
}

// slot = off[row]++ ; csr[slot] = {col, w} via 8B atomicExch (plain scattered
// stores write back a full 64B line each -> 52MB HBM writes; atomics count
// operand size only). After this, off[i] == segment END.
__global__ void k_fill(const int* __restrict__ row, const int* __restrict__ col,
                       const float* __restrict__ ew, const float* __restrict__ dis,
                       int* __restrict__ off, unsigned long long* __restrict__ csr,
                       int ne) {
    int i = blockIdx.x * blockDim.x + threadIdx.x;
    if (i >= ne) return;
    int r = row[i], c = col[i];
    float w = dis[r] * ew[i] * dis[c];
    int slot = atomicAdd(&off[r], 1);
    unsigned long long payload =
        (unsigned long long)(unsigned int)c |
        ((unsigned long long)(unsigned int)__float_as_int(w) << 32);
    atomicExch(&csr[slot], payload);
}

// ---- dense: Y[nrows,64] = op(X) @ W[64,64]; op = relu(x+bias) if RELU_BIAS --

template <bool RELU_BIAS>
__global__ __launch_bounds__(256) void k_gemm64(const float* __restrict__ X,
                                                const float* __restrict__ W,
                                                const float* __restrict__ bias_in,
                                                float* __restrict__ Y, int nrows) {
    __shared__ float Wl[64 * 64];   // [k][f]
    __shared__ float XT[64 * 68];   // [k][r], padded
    int tid = threadIdx.x;
    int r0 = blockIdx.x * 64;
    for (int i = tid; i < 64 * 64; i += 256) Wl[i] = W[i];
    for (int i = tid; i < 64 * 64; i += 256) {
        int r = i >> 6, k = i & 63;
        int rr = r0 + r;
        float v = 0.f;
        if (rr < nrows) {
            v = X[(size_t)r0 * 64 + i];
            if (RELU_BIAS) v = fmaxf(v + bias_in[k], 0.f);
        }
        XT[k * 68 + r] = v;
    }
    __syncthreads();
    int f4 = (tid & 15) * 4;
    int r4 = (tid >> 4) * 4;
    float acc[4][4];
#pragma unroll
    for (int i = 0; i < 4; ++i)
#pragma unroll
        for (int j = 0; j < 4; ++j) acc[i][j] = 0.f;
#pragma unroll 8
    for (int k = 0; k < 64; ++k) {
        float4 w = *(const float4*)&Wl[k * 64 + f4];
        float4 xv = *(const float4*)&XT[k * 68 + r4];
        float xs[4] = {xv.x, xv.y, xv.z, xv.w};
        float ws[4] = {w.x, w.y, w.z, w.w};
#pragma unroll
        for (int i = 0; i < 4; ++i)
#pragma unroll
            for (int j = 0; j < 4; ++j) acc[i][j] = fmaf(xs[i], ws[j], acc[i][j]);
    }
#pragma unroll
    for (int i = 0; i < 4; ++i) {
        int rr = r0 + r4 + i;
        if (rr < nrows) {
            float4 o = make_float4(acc[i][0], acc[i][1], acc[i][2], acc[i][3]);
            *(float4*)&Y[(size_t)rr * 64 + f4] = o;
        }
    }
}

// ---- pull aggregation: AGG[i] = dis[i]^2*H[i] + sum_in w*H[c] ------------
// wave per node; lanes = (sub-edge 0..3) x (feat-quad 0..15); unroll x2 ->
// 8 independent 1KB gathers in flight per wave.

__global__ __launch_bounds__(256) void k_agg(const int* __restrict__ off_end,
                                             const int* __restrict__ cnt,
                                             const float* __restrict__ dis,
                                             const int2* __restrict__ csr,
                                             const float* __restrict__ H,
                                             float* __restrict__ AGG, int n) {
    int l = threadIdx.x & 63;
    int node = (blockIdx.x * blockDim.x + threadIdx.x) >> 6;
    if (node >= n) return;
    int sub = l >> 4;
    int q4 = (l & 15) * 4;
    int endv = off_end[node];
    int s = endv - cnt[node];
    float4 acc = make_float4(0.f, 0.f, 0.f, 0.f);
    int e = s + sub;
    for (; e + 4 < endv; e += 8) {
        int2 p0 = csr[e];
        int2 p1 = csr[e + 4];
        float w0 = __int_as_float(p0.y);
        float w1 = __int_as_float(p1.y);
        float4 h0 = *(const float4*)&H[(size_t)p0.x * 64 + q4];
        float4 h1 = *(const float4*)&H[(size_t)p1.x * 64 + q4];
        acc.x = fmaf(w0, h0.x, acc.x);
        acc.y = fmaf(w0, h0.y, acc.y);
        acc.z = fmaf(w0, h0.z, acc.z);
        acc.w = fmaf(w0, h0.w, acc.w);
        acc.x = fmaf(w1, h1.x, acc.x);
        acc.y = fmaf(w1, h1.y, acc.y);
        acc.z = fmaf(w1, h1.z, acc.z);
        acc.w = fmaf(w1, h1.w, acc.w);
    }
    if (e < endv) {
        int2 p = csr[e];
        float w = __int_as_float(p.y);
        float4 h = *(const float4*)&H[(size_t)p.x * 64 + q4];
        acc.x = fmaf(w, h.x, acc.x);
        acc.y = fmaf(w, h.y, acc.y);
        acc.z = fmaf(w, h.z, acc.z);
        acc.w = fmaf(w, h.w, acc.w);
    }
#pragma unroll
    for (int m = 16; m <= 32; m <<= 1) {
        acc.x += __shfl_xor(acc.x, m, 64);
        acc.y += __shfl_xor(acc.y, m, 64);
        acc.z += __shfl_xor(acc.z, m, 64);
        acc.w += __shfl_xor(acc.w, m, 64);
    }
    if (sub == 0) {
        float d = dis[node];
        float d2 = d * d;
        float4 hs = *(const float4*)&H[(size_t)node * 64 + q4];
        acc.x = fmaf(d2, hs.x, acc.x);
        acc.y = fmaf(d2, hs.y, acc.y);
        acc.z = fmaf(d2, hs.z, acc.z);
        acc.w = fmaf(d2, hs.w, acc.w);
        *(float4*)&AGG[(size_t)node * 64 + q4] = acc;
    }
}

// ---- fused MLP head: out = relu((AGG+b2)@fc1 + fc1b) @ fc2 + fc2b --------

__global__ __launch_bounds__(256, 4) void k_mlp(const float* __restrict__ AGG,
                                                const float* __restrict__ b2,
                                                const float* __restrict__ fc1w,
                                                const float* __restrict__ fc1b,
                                                const float* __restrict__ fc2w,
                                                const float* __restrict__ fc2b,
                                                float* __restrict__ out, int n) {
    __shared__ float XT[64 * 68];    // [k][r] transposed input tile
    __shared__ float Wh[64 * 64];    // one 64-col half of fc1w
    __shared__ float W2l[128 * 10];
    __shared__ float b1l[128];
    __shared__ float b2c[16];
    int tid = threadIdx.x;
    int r0 = blockIdx.x * 64;
    for (int i = tid; i < 64 * 64; i += 256) {
        int r = i >> 6, k = i & 63;
        int rr = r0 + r;
        float v = 0.f;
        if (rr < n) v = AGG[(size_t)r0 * 64 + i] + b2[k];
        XT[k * 68 + r] = v;
    }
    for (int i = tid; i < 64 * 64; i += 256)
        Wh[i] = fc1w[(i >> 6) * 128 + (i & 63)];
    for (int i = tid; i < 128 * 10; i += 256) W2l[i] = fc2w[i];
    if (tid < 128) b1l[tid] = fc1b[tid];
    if (tid < 10) b2c[tid] = fc2b[tid];
    __syncthreads();

    int f4 = (tid & 15) * 4;
    int r4 = (tid >> 4) * 4;
    float pacc[4][10];
#pragma unroll
    for (int i = 0; i < 4; ++i)
#pragma unroll
        for (int c = 0; c < 10; ++c) pacc[i][c] = 0.f;

#pragma unroll
    for (int h = 0; h < 2; ++h) {
        if (h == 1) {
            __syncthreads();
            for (int i = tid; i < 64 * 64; i += 256)
                Wh[i] = fc1w[(i >> 6) * 128 + 64 + (i & 63)];
            __syncthreads();
        }
        float acc[4][4];
#pragma unroll
        for (int i = 0; i < 4; ++i)
#pragma unroll
            for (int j = 0; j < 4; ++j) acc[i][j] = 0.f;
#pragma unroll 8
        for (int k = 0; k < 64; ++k) {
            float4 xv = *(const float4*)&XT[k * 68 + r4];
            float4 wv = *(const float4*)&Wh[k * 64 + f4];
            float xs[4] = {xv.x, xv.y, xv.z, xv.w};
            float ws[4] = {wv.x, wv.y, wv.z, wv.w};
#pragma unroll
            for (int i = 0; i < 4; ++i)
#pragma unroll
                for (int j = 0; j < 4; ++j) acc[i][j] = fmaf(xs[i], ws[j], acc[i][j]);
        }
#pragma unroll
        for (int jj = 0; jj < 4; ++jj) {
            int jcol = h * 64 + f4 + jj;
            float w2r[10];
#pragma unroll
            for (int c = 0; c < 10; ++c) w2r[c] = W2l[jcol * 10 + c];
            float bj = b1l[jcol];
#pragma unroll
            for (int i = 0; i < 4; ++i) {
                float pv = fmaxf(acc[i][jj] + bj, 0.f);
#pragma unroll
                for (int c = 0; c < 10; ++c) pacc[i][c] = fmaf(pv, w2r[c], pacc[i][c]);
            }
        }
    }
#pragma unroll
    for (int i = 0; i < 4; ++i)
#pragma unroll
        for (int c = 0; c < 10; ++c) {
            float v = pacc[i][c];
            v += __shfl_xor(v, 1, 64);
            v += __shfl_xor(v, 2, 64);
            v += __shfl_xor(v, 4, 64);
            v += __shfl_xor(v, 8, 64);
            pacc[i][c] = v;
        }
    if ((tid & 15) == 0) {
#pragma unroll
        for (int i = 0; i < 4; ++i) {
            int rr = r0 + r4 + i;
            if (rr < n) {
#pragma unroll
                for (int c = 0; c < 10; ++c)
                    out[(size_t)rr * 10 + c] = pacc[i][c] + b2c[c];
            }
        }
    }
}

// --------------------------------------------------------------------------

extern "C" void kernel_launch(void* const* d_in, const int* in_sizes, int n_in,
                              void* d_out, int out_size, void* d_ws, size_t ws_size,
                              hipStream_t stream) {
    const float* x     = (const float*)d_in[0];
    const int*   eidx  = (const int*)d_in[1];
    const float* eattr = (const float*)d_in[2];
    const float* W1    = (const float*)d_in[3];
    const float* b1    = (const float*)d_in[4];
    const float* W2    = (const float*)d_in[5];
    const float* b2    = (const float*)d_in[6];
    const float* fc1w  = (const float*)d_in[7];
    const float* fc1b  = (const float*)d_in[8];
    const float* fc2w  = (const float*)d_in[9];
    const float* fc2b  = (const float*)d_in[10];
    float* out = (float*)d_out;

    const int N = in_sizes[0] / NFEAT;   // 50000
    const int E = in_sizes[2];           // 800000
    const int* row = eidx;
    const int* col = eidx + E;

    // workspace layout
    int*   icnt = (int*)d_ws;                  // N (padded 50176)
    int*   off  = icnt + 50176;                // N
    float* dis  = (float*)(off + 50176);       // N
    int*   bsum = (int*)(dis + 50176);         // 256
    int*   bpre = bsum + 256;                  // 256
    unsigned long long* csr = (unsigned long long*)(bpre + 256);  // E x 8B
    float* H    = (float*)(csr + E);           // N*64
    float* AGG  = H + (size_t)N * 64;          // N*64

    const int TB = 256;
    int gN = (N + TB - 1) / TB;                // 196
    int gG = (N + 63) / 64;                    // 782
    int gA = (N * 64 + TB - 1) / TB;           // 12500
    int gE1 = (E + TB - 1) / TB;               // 3125
    int nb = gN;

    hipMemsetAsync(icnt, 0, (size_t)N * sizeof(int), stream);
    k_hist<<<1024, TB, 0, stream>>>(row, icnt, E);
    k_scanA<<<nb, TB, 0, stream>>>(icnt, bsum, N);
    k_scanB<<<1, TB, 0, stream>>>(bsum, bpre, nb);
    k_scanC<<<nb, TB, 0, stream>>>(icnt, bpre, off, dis, N);
    k_fill<<<gE1, TB, 0, stream>>>(row, col, eattr, dis, off, csr, E);

    // layer 1
    k_gemm64<false><<<gG, TB, 0, stream>>>(x, W1, nullptr, H, N);
    k_agg<<<gA, TB, 0, stream>>>(off, icnt, dis, (const int2*)csr, H, AGG, N);
    // layer 2
    k_gemm64<true><<<gG, TB, 0, stream>>>(AGG, W2, b1, H, N);
    k_agg<<<gA, TB, 0, stream>>>(off, icnt, dis, (const int2*)csr, H, AGG, N);
    // MLP head
    k_mlp<<<gG, TB, 0, stream>>>(AGG, b2, fc1w, fc1b, fc2w, fc2b, out, N);
}

// Round 5
// 284.444 us; speedup vs baseline: 1.1350x; 1.1350x over previous
//
#include <hip/hip_runtime.h>

// GCN forward: 2x GCNConv(64->64) + MLP(64->128->10), fp32, pull-based CSR.
// r5: plain-store CSR fill (scattered writes cost a 64B line regardless of
// store vs atomic; atomicExch only added op-rate cost), and layer-2's
// relu(agg+b1)@W2 fused into agg1's epilogue (kills one GEMM dispatch +
// a 25.6MB AGG round-trip).

#define NFEAT 64

// ---- CSR build ----------------------------------------------------------

__global__ void k_hist(const int* __restrict__ row, int* __restrict__ cnt, int ne) {
    int i = blockIdx.x * blockDim.x + threadIdx.x;
    int st = gridDim.x * blockDim.x;
    for (; i < ne; i += st) atomicAdd(&cnt[row[i]], 1);
}

__global__ void k_scanA(const int* __restrict__ cnt, int* __restrict__ bsum, int n) {
    __shared__ int s[256];
    int tid = threadIdx.x;
    int i = blockIdx.x * 256 + tid;
    s[tid] = (i < n) ? cnt[i] : 0;
    __syncthreads();
    for (int d = 128; d > 0; d >>= 1) {
        if (tid < d) s[tid] += s[tid + d];
        __syncthreads();
    }
    if (tid == 0) bsum[blockIdx.x] = s[0];
}

__global__ void k_scanB(const int* __restrict__ bsum, int* __restrict__ bpre, int nb) {
    __shared__ int s[256];
    int tid = threadIdx.x;
    int v = (tid < nb) ? bsum[tid] : 0;
    s[tid] = v;
    __syncthreads();
    for (int d = 1; d < 256; d <<= 1) {
        int t = (tid >= d) ? s[tid - d] : 0;
        __syncthreads();
        s[tid] += t;
        __syncthreads();
    }
    if (tid < nb) bpre[tid] = s[tid] - v;  // exclusive
}

// exclusive per-element offsets + dis = rsqrt(1+deg)
__global__ void k_scanC(const int* __restrict__ cnt, const int* __restrict__ bpre,
                        int* __restrict__ off, float* __restrict__ dis, int n) {
    __shared__ int s[256];
    int tid = threadIdx.x;
    int i = blockIdx.x * 256 + tid;
    int v = (i < n) ? cnt[i] : 0;
    s[tid] = v;
    __syncthreads();
    for (int d = 1; d < 256; d <<= 1) {
        int t = (tid >= d) ? s[tid - d] : 0;
        __syncthreads();
        s[tid] += t;
        __syncthreads();
    }
    if (i < n) {
        off[i] = bpre[blockIdx.x] + s[tid] - v;
        dis[i] = rsqrtf(1.0f + (float)v);
    }
}

// slot = off[row]++ ; csr[slot] = {col, w} (plain 8B store; line-granular
// writeback is unavoidable for scattered writes). off[i] ends at segment END.
__global__ void k_fill(const int* __restrict__ row, const int* __restrict__ col,
                       const float* __restrict__ ew, const float* __restrict__ dis,
                       int* __restrict__ off, int2* __restrict__ csr, int ne) {
    int i = blockIdx.x * blockDim.x + threadIdx.x;
    if (i >= ne) return;
    int r = row[i], c = col[i];
    float w = dis[r] * ew[i] * dis[c];
    int slot = atomicAdd(&off[r], 1);
    csr[slot] = make_int2(c, __float_as_int(w));
}

// ---- dense: Y[nrows,64] = X @ W[64,64] -----------------------------------

__global__ __launch_bounds__(256) void k_gemm64(const float* __restrict__ X,
                                                const float* __restrict__ W,
                                                float* __restrict__ Y, int nrows) {
    __shared__ float Wl[64 * 64];   // [k][f]
    __shared__ float XT[64 * 68];   // [k][r], padded
    int tid = threadIdx.x;
    int r0 = blockIdx.x * 64;
    for (int i = tid; i < 64 * 64; i += 256) Wl[i] = W[i];
    for (int i = tid; i < 64 * 64; i += 256) {
        int r = i >> 6, k = i & 63;
        int rr = r0 + r;
        XT[k * 68 + r] = (rr < nrows) ? X[(size_t)r0 * 64 + i] : 0.f;
    }
    __syncthreads();
    int f4 = (tid & 15) * 4;
    int r4 = (tid >> 4) * 4;
    float acc[4][4];
#pragma unroll
    for (int i = 0; i < 4; ++i)
#pragma unroll
        for (int j = 0; j < 4; ++j) acc[i][j] = 0.f;
#pragma unroll 8
    for (int k = 0; k < 64; ++k) {
        float4 w = *(const float4*)&Wl[k * 64 + f4];
        float4 xv = *(const float4*)&XT[k * 68 + r4];
        float xs[4] = {xv.x, xv.y, xv.z, xv.w};
        float ws[4] = {w.x, w.y, w.z, w.w};
#pragma unroll
        for (int i = 0; i < 4; ++i)
#pragma unroll
            for (int j = 0; j < 4; ++j) acc[i][j] = fmaf(xs[i], ws[j], acc[i][j]);
    }
#pragma unroll
    for (int i = 0; i < 4; ++i) {
        int rr = r0 + r4 + i;
        if (rr < nrows) {
            float4 o = make_float4(acc[i][0], acc[i][1], acc[i][2], acc[i][3]);
            *(float4*)&Y[(size_t)rr * 64 + f4] = o;
        }
    }
}

// ---- agg core: returns aggregated quad (ALL lanes valid after reduce) ----

__device__ __forceinline__ float4 agg_row(const int* off_end, const int* cnt,
                                          const int2* csr, const float* H,
                                          int node, int sub, int q4) {
    int endv = off_end[node];
    int s = endv - cnt[node];
    float4 acc = make_float4(0.f, 0.f, 0.f, 0.f);
    int e = s + sub;
    for (; e + 4 < endv; e += 8) {
        int2 p0 = csr[e];
        int2 p1 = csr[e + 4];
        float w0 = __int_as_float(p0.y);
        float w1 = __int_as_float(p1.y);
        float4 h0 = *(const float4*)&H[(size_t)p0.x * 64 + q4];
        float4 h1 = *(const float4*)&H[(size_t)p1.x * 64 + q4];
        acc.x = fmaf(w0, h0.x, acc.x);
        acc.y = fmaf(w0, h0.y, acc.y);
        acc.z = fmaf(w0, h0.z, acc.z);
        acc.w = fmaf(w0, h0.w, acc.w);
        acc.x = fmaf(w1, h1.x, acc.x);
        acc.y = fmaf(w1, h1.y, acc.y);
        acc.z = fmaf(w1, h1.z, acc.z);
        acc.w = fmaf(w1, h1.w, acc.w);
    }
    if (e < endv) {
        int2 p = csr[e];
        float w = __int_as_float(p.y);
        float4 h = *(const float4*)&H[(size_t)p.x * 64 + q4];
        acc.x = fmaf(w, h.x, acc.x);
        acc.y = fmaf(w, h.y, acc.y);
        acc.z = fmaf(w, h.z, acc.z);
        acc.w = fmaf(w, h.w, acc.w);
    }
#pragma unroll
    for (int m = 16; m <= 32; m <<= 1) {
        acc.x += __shfl_xor(acc.x, m, 64);
        acc.y += __shfl_xor(acc.y, m, 64);
        acc.z += __shfl_xor(acc.z, m, 64);
        acc.w += __shfl_xor(acc.w, m, 64);
    }
    return acc;  // every lane: sum over in-edges for quad (lane&15)
}

// ---- plain agg (layer 2): AGG[i] = dis^2*H[i] + sum w*H[c] ---------------

__global__ __launch_bounds__(256) void k_agg(const int* __restrict__ off_end,
                                             const int* __restrict__ cnt,
                                             const float* __restrict__ dis,
                                             const int2* __restrict__ csr,
                                             const float* __restrict__ H,
                                             float* __restrict__ AGG, int n) {
    int l = threadIdx.x & 63;
    int node = (blockIdx.x * blockDim.x + threadIdx.x) >> 6;
    if (node >= n) return;
    int sub = l >> 4;
    int q4 = (l & 15) * 4;
    float4 acc = agg_row(off_end, cnt, csr, H, node, sub, q4);
    if (sub == 0) {
        float d = dis[node];
        float d2 = d * d;
        float4 hs = *(const float4*)&H[(size_t)node * 64 + q4];
        acc.x = fmaf(d2, hs.x, acc.x);
        acc.y = fmaf(d2, hs.y, acc.y);
        acc.z = fmaf(d2, hs.z, acc.z);
        acc.w = fmaf(d2, hs.w, acc.w);
        *(float4*)&AGG[(size_t)node * 64 + q4] = acc;
    }
}

// ---- fused agg1 + layer2 transform: H2 = relu(sym-agg(H1)+b1) @ W2 -------
// Per node: agg row (all lanes), +self +b1, relu, stash 64-float row in a
// per-wave LDS buffer, then lane f computes row @ W2[:,f] from LDS W2.

__global__ __launch_bounds__(256) void k_agg_fused(const int* __restrict__ off_end,
                                                   const int* __restrict__ cnt,
                                                   const float* __restrict__ dis,
                                                   const int2* __restrict__ csr,
                                                   const float* __restrict__ H1,
                                                   const float* __restrict__ b1,
                                                   const float* __restrict__ W2,
                                                   float* __restrict__ H2, int n) {
    __shared__ float W2l[64 * 64];   // [k][f] 16KB
    __shared__ float pbuf[4][64];    // per-wave row buffer
    int tid = threadIdx.x;
    for (int i = tid; i < 64 * 64; i += 256) W2l[i] = W2[i];
    __syncthreads();
    int l = tid & 63;
    int wv = tid >> 6;
    int sub = l >> 4;
    int q4 = (l & 15) * 4;
    int nwaves = (gridDim.x * blockDim.x) >> 6;
    for (int node = (blockIdx.x * blockDim.x + tid) >> 6; node < n; node += nwaves) {
        float4 acc = agg_row(off_end, cnt, csr, H1, node, sub, q4);
        // self-loop + bias + relu (all lanes; redundant but cached loads)
        float d = dis[node];
        float d2 = d * d;
        float4 hs = *(const float4*)&H1[(size_t)node * 64 + q4];
        float4 bq = *(const float4*)&b1[q4];
        float4 p;
        p.x = fmaxf(fmaf(d2, hs.x, acc.x) + bq.x, 0.f);
        p.y = fmaxf(fmaf(d2, hs.y, acc.y) + bq.y, 0.f);
        p.z = fmaxf(fmaf(d2, hs.z, acc.z) + bq.z, 0.f);
        p.w = fmaxf(fmaf(d2, hs.w, acc.w) + bq.w, 0.f);
        if (sub == 0) *(float4*)&pbuf[wv][q4] = p;
        // wave-synchronous LDS handoff: force wait + block compiler reordering
        asm volatile("s_waitcnt lgkmcnt(0)" ::: "memory");
        float sum = 0.f;
#pragma unroll
        for (int q = 0; q < 16; ++q) {
            float4 v = *(const float4*)&pbuf[wv][q * 4];
            sum = fmaf(v.x, W2l[(q * 4 + 0) * 64 + l], sum);
            sum = fmaf(v.y, W2l[(q * 4 + 1) * 64 + l], sum);
            sum = fmaf(v.z, W2l[(q * 4 + 2) * 64 + l], sum);
            sum = fmaf(v.w, W2l[(q * 4 + 3) * 64 + l], sum);
        }
        asm volatile("s_waitcnt lgkmcnt(0)" ::: "memory");  // reads done before next write
        H2[(size_t)node * 64 + l] = sum;
    }
}

// ---- fused MLP head: out = relu((AGG+b2)@fc1 + fc1b) @ fc2 + fc2b --------

__global__ __launch_bounds__(256, 4) void k_mlp(const float* __restrict__ AGG,
                                                const float* __restrict__ b2,
                                                const float* __restrict__ fc1w,
                                                const float* __restrict__ fc1b,
                                                const float* __restrict__ fc2w,
                                                const float* __restrict__ fc2b,
                                                float* __restrict__ out, int n) {
    __shared__ float XT[64 * 68];    // [k][r] transposed input tile
    __shared__ float Wh[64 * 64];    // one 64-col half of fc1w
    __shared__ float W2l[128 * 10];
    __shared__ float b1l[128];
    __shared__ float b2c[16];
    int tid = threadIdx.x;
    int r0 = blockIdx.x * 64;
    for (int i = tid; i < 64 * 64; i += 256) {
        int r = i >> 6, k = i & 63;
        int rr = r0 + r;
        float v = 0.f;
        if (rr < n) v = AGG[(size_t)r0 * 64 + i] + b2[k];
        XT[k * 68 + r] = v;
    }
    for (int i = tid; i < 64 * 64; i += 256)
        Wh[i] = fc1w[(i >> 6) * 128 + (i & 63)];
    for (int i = tid; i < 128 * 10; i += 256) W2l[i] = fc2w[i];
    if (tid < 128) b1l[tid] = fc1b[tid];
    if (tid < 10) b2c[tid] = fc2b[tid];
    __syncthreads();

    int f4 = (tid & 15) * 4;
    int r4 = (tid >> 4) * 4;
    float pacc[4][10];
#pragma unroll
    for (int i = 0; i < 4; ++i)
#pragma unroll
        for (int c = 0; c < 10; ++c) pacc[i][c] = 0.f;

#pragma unroll
    for (int h = 0; h < 2; ++h) {
        if (h == 1) {
            __syncthreads();
            for (int i = tid; i < 64 * 64; i += 256)
                Wh[i] = fc1w[(i >> 6) * 128 + 64 + (i & 63)];
            __syncthreads();
        }
        float acc[4][4];
#pragma unroll
        for (int i = 0; i < 4; ++i)
#pragma unroll
            for (int j = 0; j < 4; ++j) acc[i][j] = 0.f;
#pragma unroll 8
        for (int k = 0; k < 64; ++k) {
            float4 xv = *(const float4*)&XT[k * 68 + r4];
            float4 wv = *(const float4*)&Wh[k * 64 + f4];
            float xs[4] = {xv.x, xv.y, xv.z, xv.w};
            float ws[4] = {wv.x, wv.y, wv.z, wv.w};
#pragma unroll
            for (int i = 0; i < 4; ++i)
#pragma unroll
                for (int j = 0; j < 4; ++j) acc[i][j] = fmaf(xs[i], ws[j], acc[i][j]);
        }
#pragma unroll
        for (int jj = 0; jj < 4; ++jj) {
            int jcol = h * 64 + f4 + jj;
            float w2r[10];
#pragma unroll
            for (int c = 0; c < 10; ++c) w2r[c] = W2l[jcol * 10 + c];
            float bj = b1l[jcol];
#pragma unroll
            for (int i = 0; i < 4; ++i) {
                float pv = fmaxf(acc[i][jj] + bj, 0.f);
#pragma unroll
                for (int c = 0; c < 10; ++c) pacc[i][c] = fmaf(pv, w2r[c], pacc[i][c]);
            }
        }
    }
#pragma unroll
    for (int i = 0; i < 4; ++i)
#pragma unroll
        for (int c = 0; c < 10; ++c) {
            float v = pacc[i][c];
            v += __shfl_xor(v, 1, 64);
            v += __shfl_xor(v, 2, 64);
            v += __shfl_xor(v, 4, 64);
            v += __shfl_xor(v, 8, 64);
            pacc[i][c] = v;
        }
    if ((tid & 15) == 0) {
#pragma unroll
        for (int i = 0; i < 4; ++i) {
            int rr = r0 + r4 + i;
            if (rr < n) {
#pragma unroll
                for (int c = 0; c < 10; ++c)
                    out[(size_t)rr * 10 + c] = pacc[i][c] + b2c[c];
            }
        }
    }
}

// --------------------------------------------------------------------------

extern "C" void kernel_launch(void* const* d_in, const int* in_sizes, int n_in,
                              void* d_out, int out_size, void* d_ws, size_t ws_size,
                              hipStream_t stream) {
    const float* x     = (const float*)d_in[0];
    const int*   eidx  = (const int*)d_in[1];
    const float* eattr = (const float*)d_in[2];
    const float* W1    = (const float*)d_in[3];
    const float* b1    = (const float*)d_in[4];
    const float* W2    = (const float*)d_in[5];
    const float* b2    = (const float*)d_in[6];
    const float* fc1w  = (const float*)d_in[7];
    const float* fc1b  = (const float*)d_in[8];
    const float* fc2w  = (const float*)d_in[9];
    const float* fc2b  = (const float*)d_in[10];
    float* out = (float*)d_out;

    const int N = in_sizes[0] / NFEAT;   // 50000
    const int E = in_sizes[2];           // 800000
    const int* row = eidx;
    const int* col = eidx + E;

    // workspace layout
    int*   icnt = (int*)d_ws;                  // N (padded 50176)
    int*   off  = icnt + 50176;                // N
    float* dis  = (float*)(off + 50176);       // N
    int*   bsum = (int*)(dis + 50176);         // 256
    int*   bpre = bsum + 256;                  // 256
    int2*  csr  = (int2*)(bpre + 256);         // E x 8B
    float* H    = (float*)(csr + E);           // N*64
    float* AGG  = H + (size_t)N * 64;          // N*64

    const int TB = 256;
    int gN = (N + TB - 1) / TB;                // 196
    int gG = (N + 63) / 64;                    // 782
    int gA = (N * 64 + TB - 1) / TB;           // 12500
    int gE1 = (E + TB - 1) / TB;               // 3125
    int nb = gN;

    hipMemsetAsync(icnt, 0, (size_t)N * sizeof(int), stream);
    k_hist<<<1024, TB, 0, stream>>>(row, icnt, E);
    k_scanA<<<nb, TB, 0, stream>>>(icnt, bsum, N);
    k_scanB<<<1, TB, 0, stream>>>(bsum, bpre, nb);
    k_scanC<<<nb, TB, 0, stream>>>(icnt, bpre, off, dis, N);
    k_fill<<<gE1, TB, 0, stream>>>(row, col, eattr, dis, off, csr, E);

    // layer 1 GEMM
    k_gemm64<<<gG, TB, 0, stream>>>(x, W1, H, N);
    // agg1 + relu(.+b1)@W2 fused -> AGG holds H2 (layer-2 features)
    k_agg_fused<<<2048, TB, 0, stream>>>(off, icnt, dis, csr, H, b1, W2, AGG, N);
    // agg2 (plain) -> H holds conv2 pre-bias output
    k_agg<<<gA, TB, 0, stream>>>(off, icnt, dis, csr, AGG, H, N);
    // MLP head (adds b2 inside)
    k_mlp<<<gG, TB, 0, stream>>>(H, b2, fc1w, fc1b, fc2w, fc2b, out, N);
}